// Round 16
// baseline (186.216 us; speedup 1.0000x reference)
//
#include <hip/hip_runtime.h>
#include <stdint.h>

// Problem constants
#define B_  2
#define S_  2048
#define D_  1024
#define H_  16
#define DK_ 64

typedef unsigned short u16;
typedef __attribute__((ext_vector_type(8))) __bf16 bf16x8;
typedef __attribute__((ext_vector_type(4))) float f32x4;
typedef __attribute__((ext_vector_type(16))) float f32x16;
typedef __attribute__((ext_vector_type(4))) short short4v;
typedef __attribute__((ext_vector_type(8))) short short8v;

// f32 -> bf16 round-to-nearest-even (scalar, epilogue use)
static __device__ __forceinline__ u16 f2bf(float f) {
    union { float f; uint32_t u; } v; v.f = f;
    return (u16)((v.u + 0x7fffu + ((v.u >> 16) & 1u)) >> 16);
}
static __device__ __forceinline__ uint32_t pk2bf(float x, float y) {
    return (uint32_t)f2bf(x) | ((uint32_t)f2bf(y) << 16);
}
// HW packed f32x2 -> bf16x2 (RNE) — 1 VALU op (T12 primitive)
static __device__ __forceinline__ uint32_t cvtpk_bf16(float lo, float hi) {
    uint32_t r; asm("v_cvt_pk_bf16_f32 %0, %1, %2" : "=v"(r) : "v"(lo), "v"(hi));
    return r;
}
// raw 2^x
static __device__ __forceinline__ float exp2f_fast(float x) {
    float r; asm("v_exp_f32 %0, %1" : "=v"(r) : "v"(x)); return r;
}

// async global->LDS, 16B per lane. LDS dest = wave-uniform base + lane*16.
#define GLOAD16(gp, lp) \
    __builtin_amdgcn_global_load_lds((const __attribute__((address_space(1))) void*)(gp), \
                                     (__attribute__((address_space(3))) void*)(lp), 16, 0, 0)

// Universal LDS 16B-slot swizzle: phys = lin ^ ((lin>>3)&7). Involution.
static __device__ __forceinline__ int swz(int lin) { return lin ^ ((lin >> 3) & 7); }

// XCD-aware bijective block swizzle (nwg % 8 == 0): physical bid -> logical.
static __device__ __forceinline__ int xcd_swz(int bid, int cpx) {
    return (bid & 7) * cpx + (bid >> 3);
}

// ------------------------------------------------------------- fused cast
__global__ __launch_bounds__(256) void cast_all_kernel(
        const float* __restrict__ q, const float* __restrict__ k, const float* __restrict__ v,
        const float* __restrict__ Wq, const float* __restrict__ Wk,
        const float* __restrict__ Wv, const float* __restrict__ Wo,
        u16* __restrict__ qb, u16* __restrict__ kb, u16* __restrict__ vb,
        u16* __restrict__ Wqb, u16* __restrict__ Wkb, u16* __restrict__ Wvb,
        u16* __restrict__ Wob) {
    int blk = blockIdx.x;
    const float* src; u16* dst; int off;
    if (blk < 2048)      { src = q;  dst = qb;  off = blk; }
    else if (blk < 4096) { src = k;  dst = kb;  off = blk - 2048; }
    else if (blk < 6144) { src = v;  dst = vb;  off = blk - 4096; }
    else if (blk < 6656) { src = Wq; dst = Wqb; off = blk - 6144; }
    else if (blk < 7168) { src = Wk; dst = Wkb; off = blk - 6656; }
    else if (blk < 7680) { src = Wv; dst = Wvb; off = blk - 7168; }
    else                 { src = Wo; dst = Wob; off = blk - 7680; }
    int i = (off * 256 + threadIdx.x) * 8;
    float4 a = *(const float4*)(src + i);
    float4 b = *(const float4*)(src + i + 4);
    uint4 r;
    r.x = pk2bf(a.x, a.y); r.y = pk2bf(a.z, a.w);
    r.z = pk2bf(b.x, b.y); r.w = pk2bf(b.z, b.w);
    *(uint4*)(void*)(dst + i) = r;
}

// ---------------------------------------------------------------------------
// QKV projection: 256x256 tile, BK=64, 8 waves (2Mx4N), 8-phase schedule.
// (unchanged from R7 working version)
// ---------------------------------------------------------------------------
__device__ __forceinline__ void stage_half(const u16* __restrict__ src,
        int R0, int kt, u16* dst, int tid) {
#pragma unroll
    for (int r = 0; r < 2; ++r) {
        int s = tid + (r << 9);                 // 512 threads, 1024 slots
        int lin = s ^ ((s >> 3) & 7);           // inverse swizzle (involution)
        int row = lin >> 3, ch = lin & 7;       // 128B rows: 8 chunks of 16B
        GLOAD16(src + (size_t)(R0 + row) * 1024 + (kt << 6) + (ch << 3),
                (char*)dst + ((r << 9) + ((tid >> 6) << 6)) * 16);
    }
}

#define VM4  asm volatile("s_waitcnt vmcnt(4)" ::: "memory")
#define VM0  asm volatile("s_waitcnt vmcnt(0)" ::: "memory")

#define PHASE(QQ, MP, LOADB, STAGE_STMT, VM_STMT)                                \
    {                                                                            \
        bf16x8 afr[2][2];                                                        \
        if (LOADB) {                                                             \
            _Pragma("unroll") for (int fn = 0; fn < 4; ++fn)                     \
            _Pragma("unroll") for (int ks = 0; ks < 2; ++ks) {                   \
                int lin = (brow0 + fn * 16 + (lane & 15)) * 8 + ks * 4 + (lane >> 4); \
                bfr[fn][ks] = *(const bf16x8*)(Bhb[QQ] + swz(lin) * 16);         \
            }                                                                    \
        }                                                                        \
        _Pragma("unroll") for (int fo = 0; fo < 2; ++fo)                         \
        _Pragma("unroll") for (int ks = 0; ks < 2; ++ks) {                       \
            int lin = ((MP) * 32 + fo * 16 + (lane & 15)) * 8 + ks * 4 + (lane >> 4); \
            afr[fo][ks] = *(const bf16x8*)(Ahb[QQ] + swz(lin) * 16);             \
        }                                                                        \
        STAGE_STMT;                                                              \
        VM_STMT;                                                                 \
        __builtin_amdgcn_s_barrier();                                            \
        __builtin_amdgcn_sched_barrier(0);                                       \
        __builtin_amdgcn_s_setprio(1);                                           \
        _Pragma("unroll") for (int fo = 0; fo < 2; ++fo)                         \
        _Pragma("unroll") for (int ks = 0; ks < 2; ++ks)                         \
        _Pragma("unroll") for (int fn = 0; fn < 4; ++fn)                         \
            acc[(MP) * 2 + fo][fn] = __builtin_amdgcn_mfma_f32_16x16x32_bf16(    \
                afr[fo][ks], bfr[fn][ks], acc[(MP) * 2 + fo][fn], 0, 0, 0);      \
        __builtin_amdgcn_s_setprio(0);                                           \
        __builtin_amdgcn_s_barrier();                                            \
        __builtin_amdgcn_sched_barrier(0);                                       \
    }

__global__ __launch_bounds__(512, 2) void qkv256_kernel(
        const u16* __restrict__ qX, const u16* __restrict__ kX, const u16* __restrict__ vX,
        const u16* __restrict__ Wq, const u16* __restrict__ Wk, const u16* __restrict__ Wv,
        const float* __restrict__ bq, const float* __restrict__ bk, const float* __restrict__ bv,
        u16* __restrict__ qo, u16* __restrict__ ko, u16* __restrict__ vt) {
    __shared__ __align__(16) u16 lds[65536];    // 128 KB
    const int tid = threadIdx.x, lane = tid & 63, w = tid >> 6;
    const int wm = w >> 2, wn = w & 3;          // 2 x 4 waves
    const int lg = xcd_swz(blockIdx.x, 24);     // 192 = 8 * 24
    const int which = lg >> 6;                  // 0=Q 1=K 2=V
    const int rem = lg & 63;
    const int n0 = (rem >> 4) << 8;             // 4 n-tiles
    const int m0 = (rem & 15) << 8;             // 16 m-tiles (m-minor: share W panel)
    const u16* X = which == 0 ? qX : (which == 1 ? kX : vX);
    const u16* W = which == 0 ? Wq : (which == 1 ? Wk : Wv);
    const float* bias = which == 0 ? bq : (which == 1 ? bk : bv);

    u16* Abase = lds;              // [dbuf][half][1024 slots]
    u16* Bbase = lds + 32768;

    // prologue: tile0 {A0,A1,B0,B1}; tile1 {B0,B1}
    stage_half(X, m0,        0, Abase + 0,             tid);
    stage_half(X, m0 + 128,  0, Abase + 8192,          tid);
    stage_half(W, n0,        0, Bbase + 0,             tid);
    stage_half(W, n0 + 128,  0, Bbase + 8192,          tid);
    stage_half(W, n0,        1, Bbase + 16384,         tid);
    stage_half(W, n0 + 128,  1, Bbase + 16384 + 8192,  tid);
    VM4;                                         // tile0's 4 halves landed
    __builtin_amdgcn_s_barrier();
    __builtin_amdgcn_sched_barrier(0);

    f32x4 acc[8][4] = {};
    bf16x8 bfr[4][2];
    const char* Ahb[2] = { (const char*)(Abase + wm * 8192),
                           (const char*)(Abase + 16384 + wm * 8192) };
    const char* Bhb[2] = { (const char*)(Bbase + (wn >> 1) * 8192),
                           (const char*)(Bbase + 16384 + (wn >> 1) * 8192) };
    const int brow0 = (wn & 1) * 64;

#pragma unroll 1
    for (int i = 0; i < 8; ++i) {
        const int t0 = 2 * i, t1 = 2 * i + 1;
        const bool nl = (i < 7);                 // not-last
        // p1..p4: compute t0 (buf 0)
        PHASE(0, 0, true,  stage_half(X, m0,       t1,     Abase + 16384,        tid), (void)0);
        PHASE(0, 1, false, stage_half(X, m0 + 128, t1,     Abase + 16384 + 8192, tid), (void)0);
        PHASE(0, 2, false, if (nl) stage_half(W, n0,       t0 + 2, Bbase + 0,    tid), (void)0);
        PHASE(0, 3, false, if (nl) stage_half(W, n0 + 128, t0 + 2, Bbase + 8192, tid),
              if (nl) { VM4; } else { VM0; });
        // p5..p8: compute t1 (buf 1)
        PHASE(1, 0, true,  if (nl) stage_half(X, m0,       t0 + 2, Abase + 0,    tid), (void)0);
        PHASE(1, 1, false, if (nl) stage_half(X, m0 + 128, t0 + 2, Abase + 8192, tid), (void)0);
        PHASE(1, 2, false, if (nl) stage_half(W, n0,       t1 + 2, Bbase + 16384, tid), (void)0);
        PHASE(1, 3, false, if (nl) stage_half(W, n0 + 128, t1 + 2, Bbase + 16384 + 8192, tid),
              if (nl) { VM4; });
    }

    // ---------------- epilogues
    if (which < 2) {
        u16* out = which == 0 ? qo : ko;
        const float scale = which == 0 ? 0.1803368801111883f : 1.0f; // (1/8)*log2(e)
#pragma unroll
        for (int fn = 0; fn < 4; ++fn) {
            int n = n0 + wn * 64 + fn * 16 + (lane & 15);
            float bb = bias[n];
            int h = n >> 6, dk = n & 63;
#pragma unroll
            for (int fm = 0; fm < 8; ++fm)
#pragma unroll
                for (int j = 0; j < 4; ++j) {
                    int m = m0 + wm * 128 + fm * 16 + (lane >> 4) * 4 + j;
                    int b = m >> 11, s = m & 2047;
                    out[((size_t)(b * H_ + h) * S_ + s) * DK_ + dk] =
                        f2bf((acc[fm][fn][j] + bb) * scale);
                }
        }
    } else {
        // V: per-wave private 16KB LDS transpose [128 s][64 dk] -> [64 dk][128 s]
        __syncthreads();                         // all compute LDS reads done
        u16* wl = lds + w * 8192;
#pragma unroll
        for (int fn = 0; fn < 4; ++fn) {
            int dk = fn * 16 + (lane & 15);
            float bb = bias[n0 + wn * 64 + dk];
            int xr = (dk & 7) << 3;
#pragma unroll
            for (int fm = 0; fm < 8; ++fm) {
                int sl = fm * 16 + (lane >> 4) * 4;
                short4v p;
#pragma unroll
                for (int j = 0; j < 4; ++j) p[j] = (short)f2bf(acc[fm][fn][j] + bb);
                *(short4v*)(void*)&wl[dk * 128 + (sl ^ xr)] = p;
            }
        }
        int mrow = m0 + wm * 128;
        int b = mrow >> 11, sbase = mrow & 2047;
        int h = (n0 >> 6) + wn;
        u16* dst = vt + ((size_t)(b * H_ + h) * DK_) * S_ + sbase;
#pragma unroll
        for (int oc = 0; oc < 8; ++oc)
#pragma unroll
            for (int ic = 0; ic < 2; ++ic) {
                int dk = oc * 8 + (lane >> 3);
                int sc = ic * 8 + (lane & 7);
                short8v vv = *(const short8v*)(const void*)
                    &wl[dk * 128 + ((sc * 8) ^ ((dk & 7) << 3))];
                *(short8v*)(void*)(dst + (size_t)dk * S_ + sc * 8) = vv;
            }
    }
}

// ---------------------- Output projection: 64x128 tile, 2-phase dbuf.
// (unchanged from R15 — 512 blocks, 2 blocks/CU)
__global__ __launch_bounds__(256) void oproj_kernel(
        const u16* __restrict__ X, const u16* __restrict__ W,
        const float* __restrict__ bias, float* __restrict__ out) {
    __shared__ __align__(16) u16 lds[12288];
    const int tid = threadIdx.x, lane = tid & 63, w = tid >> 6;
    const int wm = w >> 1, wn = w & 1;
    const int bid = xcd_swz(blockIdx.x, 64);    // 512 = 8 * 64
    const int m0 = (bid >> 3) << 6;             // 64 m-tiles of 64 rows
    const int n0 = (bid & 7) << 7;              // 8 n-tiles of 128 cols
    u16* As = lds;          // [2][2048]
    u16* Bs = lds + 4096;   // [2][4096]

    auto stage = [&](int bi, int kt) {
        {   // A: 64x32 = 256 slots, 1 load/thread
            int lin = tid ^ ((tid >> 3) & 7);
            int row = lin >> 2, ch = lin & 3;
            GLOAD16(X + (size_t)(m0 + row) * 1024 + (kt << 5) + (ch << 3),
                    (char*)(As + bi * 2048) + (w << 6) * 16);
        }
#pragma unroll
        for (int r = 0; r < 2; ++r) {   // B: 128x32 = 512 slots, 2 loads/thread
            int s = tid + (r << 8);
            int lin = s ^ ((s >> 3) & 7);
            int row = lin >> 2, ch = lin & 3;
            GLOAD16(W + (size_t)(n0 + row) * 1024 + (kt << 5) + (ch << 3),
                    (char*)(Bs + bi * 4096) + ((r << 8) + (w << 6)) * 16);
        }
    };

    f32x4 acc[2][4] = {};
    stage(0, 0);
    asm volatile("s_waitcnt vmcnt(0)" ::: "memory");
    __syncthreads();
#pragma unroll 1
    for (int kt = 0; kt < 32; ++kt) {
        const int cur = kt & 1;
        if (kt < 31) stage(cur ^ 1, kt + 1);    // prefetch next tile (in flight)
        const char* Ab = (const char*)(As + cur * 2048);
        const char* Bb = (const char*)(Bs + cur * 4096);
        bf16x8 a[2], b[4];
#pragma unroll
        for (int f = 0; f < 2; ++f) {
            int rowa = wm * 32 + f * 16 + (lane & 15);
            a[f] = *(const bf16x8*)(Ab + swz(rowa * 4 + (lane >> 4)) * 16);
        }
#pragma unroll
        for (int f = 0; f < 4; ++f) {
            int rowb = wn * 64 + f * 16 + (lane & 15);
            b[f] = *(const bf16x8*)(Bb + swz(rowb * 4 + (lane >> 4)) * 16);
        }
#pragma unroll
        for (int fm = 0; fm < 2; ++fm)
#pragma unroll
            for (int fn = 0; fn < 4; ++fn)
                acc[fm][fn] = __builtin_amdgcn_mfma_f32_16x16x32_bf16(
                    a[fm], b[fn], acc[fm][fn], 0, 0, 0);
        __syncthreads();   // drains vmcnt (prefetch landed) + lgkm, guards buf reuse
    }

    // epilogue: + bias, fp32 store
#pragma unroll
    for (int fn = 0; fn < 4; ++fn) {
        int n = n0 + wn * 64 + fn * 16 + (lane & 15);
        float bb = bias[n];
#pragma unroll
        for (int fm = 0; fm < 2; ++fm)
#pragma unroll
            for (int j = 0; j < 4; ++j) {
                int m = m0 + wm * 32 + fm * 16 + (lane >> 4) * 4 + j;
                out[(size_t)m * 1024 + n] = acc[fm][fn][j] + bb;
            }
    }
}

// ------------------------------------------------------------ flash attention
// NO-LDS version: K/V fragments loaded straight from global into registers.
// K/V are L2-resident (XCD working set ~2MB < 4MB L2; FETCH already ~12MB).
// Removes: staging, the KV ring, ALL barriers -> the 8 waves/CU desynchronize
// and the convoy stall (wall - max pipe) disappears. A wave reads, per tile,
// 16x global_load_dwordx4 (32 rows x 32B contiguous per row; the 4 c-chunks
// cover each row's 128B so L1 coalesces). Math identical to R12.
__global__ __launch_bounds__(256, 2) void attn_kernel(
        const u16* __restrict__ qh, const u16* __restrict__ kh,
        const u16* __restrict__ Vt, u16* __restrict__ ao) {
    const int tid = threadIdx.x, lane = tid & 63, w = tid >> 6;
    const int l31 = lane & 31, hh = lane >> 5;
    const int lg = xcd_swz(blockIdx.x, 64);      // 512 = 8 * 64
    const int bh = lg >> 4, qt = lg & 15;
    const u16* qg = qh + ((size_t)bh * S_ + qt * 128) * DK_;

    // per-lane K/V base pointers (loop adds kt/kb/c offsets only)
    const u16* kbase = kh + (size_t)bh * S_ * DK_ + (size_t)l31 * 64 + hh * 8;
    const u16* vbase = Vt + (size_t)bh * DK_ * S_ + (size_t)l31 * S_ + hh * 8;

    // Q fragments (B-operand): col=qrow=l31, dk = c*16 + hh*8 .. +8
    bf16x8 qf[4];
#pragma unroll
    for (int c = 0; c < 4; ++c)
        qf[c] = *(const bf16x8*)(qg + (size_t)(w * 32 + l31) * 64 + c * 16 + hh * 8);

    f32x16 acc[2] = {};
    float rs = 0.f;

#pragma unroll 1
    for (int kt = 0; kt < 32; ++kt) {
        // K fragments from global (row = kt*64 + kb*32 + l31, 32B/row here)
        const u16* kp = kbase + (size_t)(kt << 6) * 64;
        bf16x8 kf[2][4];
#pragma unroll
        for (int kb = 0; kb < 2; ++kb)
#pragma unroll
            for (int c = 0; c < 4; ++c)
                kf[kb][c] = *(const bf16x8*)(kp + (kb << 5) * 64 + (c << 4));

        // QK^T
        f32x16 st[2] = {};
#pragma unroll
        for (int kb = 0; kb < 2; ++kb) {
            __builtin_amdgcn_s_setprio(1);
#pragma unroll
            for (int c = 0; c < 4; ++c)
                st[kb] = __builtin_amdgcn_mfma_f32_32x32x16_bf16(
                    kf[kb][c], qf[c], st[kb], 0, 0, 0);
            __builtin_amdgcn_s_setprio(0);
        }

        // V fragments from global (dk-row = nb*32 + l31, key col = kt*64+...)
        const u16* vp = vbase + (kt << 6);
        bf16x8 vf[2][4];
#pragma unroll
        for (int nb = 0; nb < 2; ++nb)
#pragma unroll
            for (int c = 0; c < 4; ++c)
                vf[nb][c] = *(const bf16x8*)(vp + (size_t)(nb << 5) * S_ + (c << 4));

        // softmax numerator + in-register repack (T12)
        bf16x8 pa[4];
#pragma unroll
        for (int c = 0; c < 4; ++c) {
            const int kb = c >> 1, o = (c & 1) * 8;
            float e0 = exp2f_fast(st[kb][o + 0]);
            float e1 = exp2f_fast(st[kb][o + 1]);
            float e2 = exp2f_fast(st[kb][o + 2]);
            float e3 = exp2f_fast(st[kb][o + 3]);
            float e4 = exp2f_fast(st[kb][o + 4]);
            float e5 = exp2f_fast(st[kb][o + 5]);
            float e6 = exp2f_fast(st[kb][o + 6]);
            float e7 = exp2f_fast(st[kb][o + 7]);
            rs += ((e0 + e1) + (e2 + e3)) + ((e4 + e5) + (e6 + e7));
            uint32_t u0 = cvtpk_bf16(e0, e1);
            uint32_t u1 = cvtpk_bf16(e2, e3);
            uint32_t u2 = cvtpk_bf16(e4, e5);
            uint32_t u3 = cvtpk_bf16(e6, e7);
            asm volatile("v_permlane32_swap_b32 %0, %1" : "+v"(u0), "+v"(u2));
            asm volatile("v_permlane32_swap_b32 %0, %1" : "+v"(u1), "+v"(u3));
            union { uint32_t u[4]; bf16x8 v; } pu;
            pu.u[0] = u0; pu.u[1] = u1; pu.u[2] = u2; pu.u[3] = u3;
            pa[c] = pu.v;
        }

        // PV
#pragma unroll
        for (int nb = 0; nb < 2; ++nb) {
            __builtin_amdgcn_s_setprio(1);
#pragma unroll
            for (int c = 0; c < 4; ++c)
                acc[nb] = __builtin_amdgcn_mfma_f32_32x32x16_bf16(
                    pa[c], vf[nb][c], acc[nb], 0, 0, 0);
            __builtin_amdgcn_s_setprio(0);
        }
    }

    // epilogue: reduce hh-halves' row-sums, divide, store bf16
    rs += __shfl_xor(rs, 32);
    const int bb = bh >> 4, hd = bh & 15;
#pragma unroll
    for (int r = 0; r < 16; ++r) {
        int ql = (r & 3) + 8 * (r >> 2) + 4 * hh;
        float inv = 1.0f / __shfl(rs, ql);
        int srow = qt * 128 + w * 32 + ql;
#pragma unroll
        for (int nb = 0; nb < 2; ++nb) {
            int col = hd * 64 + nb * 32 + l31;
            ao[((size_t)bb * S_ + srow) * D_ + col] = f2bf(acc[nb][r] * inv);
        }
    }
}

// ---------------------------------------------------------------- launch
extern "C" void kernel_launch(void* const* d_in, const int* in_sizes, int n_in,
                              void* d_out, int out_size, void* d_ws, size_t ws_size,
                              hipStream_t stream) {
    const float* q  = (const float*)d_in[0];
    const float* k  = (const float*)d_in[1];
    const float* v  = (const float*)d_in[2];
    const float* Wq = (const float*)d_in[3];
    const float* bq = (const float*)d_in[4];
    const float* Wk = (const float*)d_in[5];
    const float* bk = (const float*)d_in[6];
    const float* Wv = (const float*)d_in[7];
    const float* bv = (const float*)d_in[8];
    const float* Wo = (const float*)d_in[9];
    const float* bo = (const float*)d_in[10];

    char* ws = (char*)d_ws;
    u16* qb  = (u16*)(ws);                  // 8 MiB
    u16* kb  = (u16*)(ws + (8u  << 20));    // 8 MiB (reused as attn-out)
    u16* vb  = (u16*)(ws + (16u << 20));    // 8 MiB
    u16* Wqb = (u16*)(ws + (24u << 20));    // 2 MiB each
    u16* Wkb = (u16*)(ws + (26u << 20));
    u16* Wvb = (u16*)(ws + (28u << 20));
    u16* Wob = (u16*)(ws + (30u << 20));
    u16* qhb = (u16*)(ws + (32u << 20));    // 8 MiB [B,H,S,DK]
    u16* khb = (u16*)(ws + (40u << 20));    // 8 MiB [B,H,S,DK]
    u16* Vtb = (u16*)(ws + (48u << 20));    // 8 MiB [BH,DK,S]
    u16* aob = kb;                          // alias: kb dead after qkv

    cast_all_kernel<<<8192, 256, 0, stream>>>(q, k, v, Wq, Wk, Wv, Wo,
                                              qb, kb, vb, Wqb, Wkb, Wvb, Wob);

    qkv256_kernel<<<192, 512, 0, stream>>>(
        qb, kb, vb, Wqb, Wkb, Wvb, bq, bk, bv, qhb, khb, Vtb);

    attn_kernel<<<512, 256, 0, stream>>>(qhb, khb, Vtb, aob);

    oproj_kernel<<<512, 256, 0, stream>>>(aob, Wob, bo, (float*)d_out);
}

// Round 17
// 113.252 us; speedup vs baseline: 1.6443x; 1.6443x over previous
//
#include <hip/hip_runtime.h>
#include <stdint.h>

// Problem constants
#define B_  2
#define S_  2048
#define D_  1024
#define H_  16
#define DK_ 64

typedef unsigned short u16;
typedef __attribute__((ext_vector_type(8))) __bf16 bf16x8;
typedef __attribute__((ext_vector_type(4))) float f32x4;
typedef __attribute__((ext_vector_type(16))) float f32x16;
typedef __attribute__((ext_vector_type(4))) short short4v;
typedef __attribute__((ext_vector_type(8))) short short8v;

// f32 -> bf16 round-to-nearest-even (scalar, epilogue use)
static __device__ __forceinline__ u16 f2bf(float f) {
    union { float f; uint32_t u; } v; v.f = f;
    return (u16)((v.u + 0x7fffu + ((v.u >> 16) & 1u)) >> 16);
}
static __device__ __forceinline__ uint32_t pk2bf(float x, float y) {
    return (uint32_t)f2bf(x) | ((uint32_t)f2bf(y) << 16);
}
// HW packed f32x2 -> bf16x2 (RNE) — 1 VALU op (T12 primitive)
static __device__ __forceinline__ uint32_t cvtpk_bf16(float lo, float hi) {
    uint32_t r; asm("v_cvt_pk_bf16_f32 %0, %1, %2" : "=v"(r) : "v"(lo), "v"(hi));
    return r;
}
// raw 2^x
static __device__ __forceinline__ float exp2f_fast(float x) {
    float r; asm("v_exp_f32 %0, %1" : "=v"(r) : "v"(x)); return r;
}

// async global->LDS, 16B per lane. LDS dest = wave-uniform base + lane*16.
#define GLOAD16(gp, lp) \
    __builtin_amdgcn_global_load_lds((const __attribute__((address_space(1))) void*)(gp), \
                                     (__attribute__((address_space(3))) void*)(lp), 16, 0, 0)

// Universal LDS 16B-slot swizzle: phys = lin ^ ((lin>>3)&7). Involution.
static __device__ __forceinline__ int swz(int lin) { return lin ^ ((lin >> 3) & 7); }
// attn swizzle: also fold row bits 3-4 into the bank-group (involution).
static __device__ __forceinline__ int swz2(int lin) {
    return lin ^ ((lin >> 3) & 7) ^ ((lin >> 6) & 3);
}

// XCD-aware bijective block swizzle (nwg % 8 == 0): physical bid -> logical.
static __device__ __forceinline__ int xcd_swz(int bid, int cpx) {
    return (bid & 7) * cpx + (bid >> 3);
}

// ------------------------------------------------------------- fused cast
__global__ __launch_bounds__(256) void cast_all_kernel(
        const float* __restrict__ q, const float* __restrict__ k, const float* __restrict__ v,
        const float* __restrict__ Wq, const float* __restrict__ Wk,
        const float* __restrict__ Wv, const float* __restrict__ Wo,
        u16* __restrict__ qb, u16* __restrict__ kb, u16* __restrict__ vb,
        u16* __restrict__ Wqb, u16* __restrict__ Wkb, u16* __restrict__ Wvb,
        u16* __restrict__ Wob) {
    int blk = blockIdx.x;
    const float* src; u16* dst; int off;
    if (blk < 2048)      { src = q;  dst = qb;  off = blk; }
    else if (blk < 4096) { src = k;  dst = kb;  off = blk - 2048; }
    else if (blk < 6144) { src = v;  dst = vb;  off = blk - 4096; }
    else if (blk < 6656) { src = Wq; dst = Wqb; off = blk - 6144; }
    else if (blk < 7168) { src = Wk; dst = Wkb; off = blk - 6656; }
    else if (blk < 7680) { src = Wv; dst = Wvb; off = blk - 7168; }
    else                 { src = Wo; dst = Wob; off = blk - 7680; }
    int i = (off * 256 + threadIdx.x) * 8;
    float4 a = *(const float4*)(src + i);
    float4 b = *(const float4*)(src + i + 4);
    uint4 r;
    r.x = pk2bf(a.x, a.y); r.y = pk2bf(a.z, a.w);
    r.z = pk2bf(b.x, b.y); r.w = pk2bf(b.z, b.w);
    *(uint4*)(void*)(dst + i) = r;
}

// ---------------------------------------------------------------------------
// QKV projection: 256x256 tile, BK=64, 8 waves (2Mx4N), 8-phase schedule.
// ---------------------------------------------------------------------------
__device__ __forceinline__ void stage_half(const u16* __restrict__ src,
        int R0, int kt, u16* dst, int tid) {
#pragma unroll
    for (int r = 0; r < 2; ++r) {
        int s = tid + (r << 9);                 // 512 threads, 1024 slots
        int lin = s ^ ((s >> 3) & 7);           // inverse swizzle (involution)
        int row = lin >> 3, ch = lin & 7;       // 128B rows: 8 chunks of 16B
        GLOAD16(src + (size_t)(R0 + row) * 1024 + (kt << 6) + (ch << 3),
                (char*)dst + ((r << 9) + ((tid >> 6) << 6)) * 16);
    }
}

#define VM4  asm volatile("s_waitcnt vmcnt(4)" ::: "memory")
#define VM0  asm volatile("s_waitcnt vmcnt(0)" ::: "memory")

#define PHASE(QQ, MP, LOADB, STAGE_STMT, VM_STMT)                                \
    {                                                                            \
        bf16x8 afr[2][2];                                                        \
        if (LOADB) {                                                             \
            _Pragma("unroll") for (int fn = 0; fn < 4; ++fn)                     \
            _Pragma("unroll") for (int ks = 0; ks < 2; ++ks) {                   \
                int lin = (brow0 + fn * 16 + (lane & 15)) * 8 + ks * 4 + (lane >> 4); \
                bfr[fn][ks] = *(const bf16x8*)(Bhb[QQ] + swz(lin) * 16);         \
            }                                                                    \
        }                                                                        \
        _Pragma("unroll") for (int fo = 0; fo < 2; ++fo)                         \
        _Pragma("unroll") for (int ks = 0; ks < 2; ++ks) {                       \
            int lin = ((MP) * 32 + fo * 16 + (lane & 15)) * 8 + ks * 4 + (lane >> 4); \
            afr[fo][ks] = *(const bf16x8*)(Ahb[QQ] + swz(lin) * 16);             \
        }                                                                        \
        STAGE_STMT;                                                              \
        VM_STMT;                                                                 \
        __builtin_amdgcn_s_barrier();                                            \
        __builtin_amdgcn_sched_barrier(0);                                       \
        __builtin_amdgcn_s_setprio(1);                                           \
        _Pragma("unroll") for (int fo = 0; fo < 2; ++fo)                         \
        _Pragma("unroll") for (int ks = 0; ks < 2; ++ks)                         \
        _Pragma("unroll") for (int fn = 0; fn < 4; ++fn)                         \
            acc[(MP) * 2 + fo][fn] = __builtin_amdgcn_mfma_f32_16x16x32_bf16(    \
                afr[fo][ks], bfr[fn][ks], acc[(MP) * 2 + fo][fn], 0, 0, 0);      \
        __builtin_amdgcn_s_setprio(0);                                           \
        __builtin_amdgcn_s_barrier();                                            \
        __builtin_amdgcn_sched_barrier(0);                                       \
    }

__global__ __launch_bounds__(512, 2) void qkv256_kernel(
        const u16* __restrict__ qX, const u16* __restrict__ kX, const u16* __restrict__ vX,
        const u16* __restrict__ Wq, const u16* __restrict__ Wk, const u16* __restrict__ Wv,
        const float* __restrict__ bq, const float* __restrict__ bk, const float* __restrict__ bv,
        u16* __restrict__ qo, u16* __restrict__ ko, u16* __restrict__ vt) {
    __shared__ __align__(16) u16 lds[65536];    // 128 KB
    const int tid = threadIdx.x, lane = tid & 63, w = tid >> 6;
    const int wm = w >> 2, wn = w & 3;          // 2 x 4 waves
    const int lg = xcd_swz(blockIdx.x, 24);     // 192 = 8 * 24
    const int which = lg >> 6;                  // 0=Q 1=K 2=V
    const int rem = lg & 63;
    const int n0 = (rem >> 4) << 8;             // 4 n-tiles
    const int m0 = (rem & 15) << 8;             // 16 m-tiles (m-minor: share W panel)
    const u16* X = which == 0 ? qX : (which == 1 ? kX : vX);
    const u16* W = which == 0 ? Wq : (which == 1 ? Wk : Wv);
    const float* bias = which == 0 ? bq : (which == 1 ? bk : bv);

    u16* Abase = lds;              // [dbuf][half][1024 slots]
    u16* Bbase = lds + 32768;

    // prologue: tile0 {A0,A1,B0,B1}; tile1 {B0,B1}
    stage_half(X, m0,        0, Abase + 0,             tid);
    stage_half(X, m0 + 128,  0, Abase + 8192,          tid);
    stage_half(W, n0,        0, Bbase + 0,             tid);
    stage_half(W, n0 + 128,  0, Bbase + 8192,          tid);
    stage_half(W, n0,        1, Bbase + 16384,         tid);
    stage_half(W, n0 + 128,  1, Bbase + 16384 + 8192,  tid);
    VM4;                                         // tile0's 4 halves landed
    __builtin_amdgcn_s_barrier();
    __builtin_amdgcn_sched_barrier(0);

    f32x4 acc[8][4] = {};
    bf16x8 bfr[4][2];
    const char* Ahb[2] = { (const char*)(Abase + wm * 8192),
                           (const char*)(Abase + 16384 + wm * 8192) };
    const char* Bhb[2] = { (const char*)(Bbase + (wn >> 1) * 8192),
                           (const char*)(Bbase + 16384 + (wn >> 1) * 8192) };
    const int brow0 = (wn & 1) * 64;

#pragma unroll 1
    for (int i = 0; i < 8; ++i) {
        const int t0 = 2 * i, t1 = 2 * i + 1;
        const bool nl = (i < 7);                 // not-last
        // p1..p4: compute t0 (buf 0)
        PHASE(0, 0, true,  stage_half(X, m0,       t1,     Abase + 16384,        tid), (void)0);
        PHASE(0, 1, false, stage_half(X, m0 + 128, t1,     Abase + 16384 + 8192, tid), (void)0);
        PHASE(0, 2, false, if (nl) stage_half(W, n0,       t0 + 2, Bbase + 0,    tid), (void)0);
        PHASE(0, 3, false, if (nl) stage_half(W, n0 + 128, t0 + 2, Bbase + 8192, tid),
              if (nl) { VM4; } else { VM0; });
        // p5..p8: compute t1 (buf 1)
        PHASE(1, 0, true,  if (nl) stage_half(X, m0,       t0 + 2, Abase + 0,    tid), (void)0);
        PHASE(1, 1, false, if (nl) stage_half(X, m0 + 128, t0 + 2, Abase + 8192, tid), (void)0);
        PHASE(1, 2, false, if (nl) stage_half(W, n0,       t1 + 2, Bbase + 16384, tid), (void)0);
        PHASE(1, 3, false, if (nl) stage_half(W, n0 + 128, t1 + 2, Bbase + 16384 + 8192, tid),
              if (nl) { VM4; });
    }

    // ---------------- epilogues
    if (which < 2) {
        u16* out = which == 0 ? qo : ko;
        const float scale = which == 0 ? 0.1803368801111883f : 1.0f; // (1/8)*log2(e)
#pragma unroll
        for (int fn = 0; fn < 4; ++fn) {
            int n = n0 + wn * 64 + fn * 16 + (lane & 15);
            float bb = bias[n];
            int h = n >> 6, dk = n & 63;
#pragma unroll
            for (int fm = 0; fm < 8; ++fm)
#pragma unroll
                for (int j = 0; j < 4; ++j) {
                    int m = m0 + wm * 128 + fm * 16 + (lane >> 4) * 4 + j;
                    int b = m >> 11, s = m & 2047;
                    out[((size_t)(b * H_ + h) * S_ + s) * DK_ + dk] =
                        f2bf((acc[fm][fn][j] + bb) * scale);
                }
        }
    } else {
        // V: per-wave private 16KB LDS transpose [128 s][64 dk] -> [64 dk][128 s]
        __syncthreads();                         // all compute LDS reads done
        u16* wl = lds + w * 8192;
#pragma unroll
        for (int fn = 0; fn < 4; ++fn) {
            int dk = fn * 16 + (lane & 15);
            float bb = bias[n0 + wn * 64 + dk];
            int xr = (dk & 7) << 3;
#pragma unroll
            for (int fm = 0; fm < 8; ++fm) {
                int sl = fm * 16 + (lane >> 4) * 4;
                short4v p;
#pragma unroll
                for (int j = 0; j < 4; ++j) p[j] = (short)f2bf(acc[fm][fn][j] + bb);
                *(short4v*)(void*)&wl[dk * 128 + (sl ^ xr)] = p;
            }
        }
        int mrow = m0 + wm * 128;
        int b = mrow >> 11, sbase = mrow & 2047;
        int h = (n0 >> 6) + wn;
        u16* dst = vt + ((size_t)(b * H_ + h) * DK_) * S_ + sbase;
#pragma unroll
        for (int oc = 0; oc < 8; ++oc)
#pragma unroll
            for (int ic = 0; ic < 2; ++ic) {
                int dk = oc * 8 + (lane >> 3);
                int sc = ic * 8 + (lane & 7);
                short8v vv = *(const short8v*)(const void*)
                    &wl[dk * 128 + ((sc * 8) ^ ((dk & 7) << 3))];
                *(short8v*)(void*)(dst + (size_t)dk * S_ + sc * 8) = vv;
            }
    }
}

// ---------------------- Output projection: 64x128 tile, 2-phase dbuf.
// Grid 512 = 64 m-tiles x 8 n-tiles -> 2 blocks/CU, 2 waves/SIMD.
__global__ __launch_bounds__(256) void oproj_kernel(
        const u16* __restrict__ X, const u16* __restrict__ W,
        const float* __restrict__ bias, float* __restrict__ out) {
    __shared__ __align__(16) u16 lds[12288];
    const int tid = threadIdx.x, lane = tid & 63, w = tid >> 6;
    const int wm = w >> 1, wn = w & 1;
    const int bid = xcd_swz(blockIdx.x, 64);    // 512 = 8 * 64
    const int m0 = (bid >> 3) << 6;             // 64 m-tiles of 64 rows
    const int n0 = (bid & 7) << 7;              // 8 n-tiles of 128 cols
    u16* As = lds;          // [2][2048]
    u16* Bs = lds + 4096;   // [2][4096]

    auto stage = [&](int bi, int kt) {
        {   // A: 64x32 = 256 slots, 1 load/thread
            int lin = tid ^ ((tid >> 3) & 7);
            int row = lin >> 2, ch = lin & 3;
            GLOAD16(X + (size_t)(m0 + row) * 1024 + (kt << 5) + (ch << 3),
                    (char*)(As + bi * 2048) + (w << 6) * 16);
        }
#pragma unroll
        for (int r = 0; r < 2; ++r) {   // B: 128x32 = 512 slots, 2 loads/thread
            int s = tid + (r << 8);
            int lin = s ^ ((s >> 3) & 7);
            int row = lin >> 2, ch = lin & 3;
            GLOAD16(W + (size_t)(n0 + row) * 1024 + (kt << 5) + (ch << 3),
                    (char*)(Bs + bi * 4096) + ((r << 8) + (w << 6)) * 16);
        }
    };

    f32x4 acc[2][4] = {};
    stage(0, 0);
    asm volatile("s_waitcnt vmcnt(0)" ::: "memory");
    __syncthreads();
#pragma unroll 1
    for (int kt = 0; kt < 32; ++kt) {
        const int cur = kt & 1;
        if (kt < 31) stage(cur ^ 1, kt + 1);    // prefetch next tile (in flight)
        const char* Ab = (const char*)(As + cur * 2048);
        const char* Bb = (const char*)(Bs + cur * 4096);
        bf16x8 a[2], b[4];
#pragma unroll
        for (int f = 0; f < 2; ++f) {
            int rowa = wm * 32 + f * 16 + (lane & 15);
            a[f] = *(const bf16x8*)(Ab + swz(rowa * 4 + (lane >> 4)) * 16);
        }
#pragma unroll
        for (int f = 0; f < 4; ++f) {
            int rowb = wn * 64 + f * 16 + (lane & 15);
            b[f] = *(const bf16x8*)(Bb + swz(rowb * 4 + (lane >> 4)) * 16);
        }
#pragma unroll
        for (int fm = 0; fm < 2; ++fm)
#pragma unroll
            for (int fn = 0; fn < 4; ++fn)
                acc[fm][fn] = __builtin_amdgcn_mfma_f32_16x16x32_bf16(
                    a[fm], b[fn], acc[fm][fn], 0, 0, 0);
        __syncthreads();   // drains vmcnt (prefetch landed) + lgkm, guards buf reuse
    }

    // epilogue: + bias, fp32 store
#pragma unroll
    for (int fn = 0; fn < 4; ++fn) {
        int n = n0 + wn * 64 + fn * 16 + (lane & 15);
        float bb = bias[n];
#pragma unroll
        for (int fm = 0; fm < 2; ++fm)
#pragma unroll
            for (int j = 0; j < 4; ++j) {
                int m = m0 + wm * 32 + fm * 16 + (lane >> 4) * 4 + j;
                out[(size_t)m * 1024 + n] = acc[fm][fn][j] + bb;
            }
    }
}

// ------------------------------------------------------------ flash attention
// R12 best-known version: 32x32x16 MFMA, hoisted addresses, 4-slot KV ring,
// 2-tile iterations, one __syncthreads per 128 keys, swz2 conflict-free,
// in-register P (cvt_pk + permlane32_swap), VALU row-sum.
__global__ __launch_bounds__(256, 2) void attn_kernel(
        const u16* __restrict__ qh, const u16* __restrict__ kh,
        const u16* __restrict__ Vt, u16* __restrict__ ao) {
    __shared__ __align__(16) u16 Ks[4][4096];    // 32KB ring [64 key][64 dk]
    __shared__ __align__(16) u16 Vs[4][4096];    // 32KB ring [64 dk][64 key]

    const int tid = threadIdx.x, lane = tid & 63, w = tid >> 6;
    const int l31 = lane & 31, hh = lane >> 5;
    const int lg = xcd_swz(blockIdx.x, 64);
    const int bh = lg >> 4, qt = lg & 15;
    const u16* qg = qh + ((size_t)bh * S_ + qt * 128) * DK_;
    const u16* kg = kh + (size_t)bh * S_ * DK_;
    const u16* vg = Vt + (size_t)bh * DK_ * S_;

    // ---- hoisted stage addressing (loop: just + kt*stride, + slot*8192)
    const int lin0 = swz2(tid), lin1 = swz2(tid + 256);
    const u16* ksrc0 = kg + (lin0 >> 3) * 64 + ((lin0 & 7) << 3);
    const u16* ksrc1 = kg + (lin1 >> 3) * 64 + ((lin1 & 7) << 3);
    const u16* vsrc0 = vg + (size_t)(lin0 >> 3) * S_ + ((lin0 & 7) << 3);
    const u16* vsrc1 = vg + (size_t)(lin1 >> 3) * S_ + ((lin1 & 7) << 3);
    char* kdst0 = (char*)(&Ks[0][0]) + (w << 6) * 16;
    char* kdst1 = (char*)(&Ks[0][0]) + (256 + (w << 6)) * 16;
    char* vdst0 = (char*)(&Vs[0][0]) + (w << 6) * 16;
    char* vdst1 = (char*)(&Vs[0][0]) + (256 + (w << 6)) * 16;

    auto stageKV = [&](int slot, int kt) {
        const int sb = slot << 13;               // slot * 8192 bytes
        GLOAD16(ksrc0 + (kt << 12), kdst0 + sb);
        GLOAD16(ksrc1 + (kt << 12), kdst1 + sb);
        GLOAD16(vsrc0 + (kt << 6),  vdst0 + sb);
        GLOAD16(vsrc1 + (kt << 6),  vdst1 + sb);
    };

    // ---- hoisted LDS read byte-offsets (same table for K and V fragments)
    int loff[2][4];
#pragma unroll
    for (int b = 0; b < 2; ++b)
#pragma unroll
        for (int c = 0; c < 4; ++c)
            loff[b][c] = swz2((b * 32 + l31) * 8 + c * 2 + hh) * 16;

    // prologue: KV tiles 0,1 + Q fragments direct from global
    stageKV(0, 0);
    stageKV(1, 1);
    bf16x8 qf[4];
#pragma unroll
    for (int c = 0; c < 4; ++c)
        qf[c] = *(const bf16x8*)(qg + (size_t)(w * 32 + l31) * 64 + c * 16 + hh * 8);
    asm volatile("s_waitcnt vmcnt(0)" ::: "memory");
    __syncthreads();

    f32x16 acc[2] = {};
    float rs = 0.f;

// QK^T of one tile into ST (2x f32x16)
#define ATTN_QK(SLOT, ST)                                                        \
    {                                                                            \
        const char* Kb = (const char*)(&Ks[0][0]) + ((SLOT) << 13);              \
        _Pragma("unroll") for (int kb = 0; kb < 2; ++kb) {                       \
            bf16x8 kf[4];                                                        \
            _Pragma("unroll") for (int c = 0; c < 4; ++c)                        \
                kf[c] = *(const bf16x8*)(Kb + loff[kb][c]);                      \
            __builtin_amdgcn_s_setprio(1);                                       \
            _Pragma("unroll") for (int c = 0; c < 4; ++c)                        \
                ST[kb] = __builtin_amdgcn_mfma_f32_32x32x16_bf16(                \
                    kf[c], qf[c], ST[kb], 0, 0, 0);                              \
            __builtin_amdgcn_s_setprio(0);                                       \
        }                                                                        \
    }

// softmax numerator + in-register repack of ST into PAOUT; rs accumulate
#define ATTN_SM(ST, PAOUT)                                                       \
    _Pragma("unroll") for (int c = 0; c < 4; ++c) {                              \
        const int kb = c >> 1, o = (c & 1) * 8;                                  \
        float e0 = exp2f_fast(ST[kb][o + 0]);                                    \
        float e1 = exp2f_fast(ST[kb][o + 1]);                                    \
        float e2 = exp2f_fast(ST[kb][o + 2]);                                    \
        float e3 = exp2f_fast(ST[kb][o + 3]);                                    \
        float e4 = exp2f_fast(ST[kb][o + 4]);                                    \
        float e5 = exp2f_fast(ST[kb][o + 5]);                                    \
        float e6 = exp2f_fast(ST[kb][o + 6]);                                    \
        float e7 = exp2f_fast(ST[kb][o + 7]);                                    \
        rs += ((e0 + e1) + (e2 + e3)) + ((e4 + e5) + (e6 + e7));                 \
        uint32_t u0 = cvtpk_bf16(e0, e1);                                        \
        uint32_t u1 = cvtpk_bf16(e2, e3);                                        \
        uint32_t u2 = cvtpk_bf16(e4, e5);                                        \
        uint32_t u3 = cvtpk_bf16(e6, e7);                                        \
        asm volatile("v_permlane32_swap_b32 %0, %1" : "+v"(u0), "+v"(u2));       \
        asm volatile("v_permlane32_swap_b32 %0, %1" : "+v"(u1), "+v"(u3));       \
        union { uint32_t u[4]; bf16x8 v; } pu;                                   \
        pu.u[0] = u0; pu.u[1] = u1; pu.u[2] = u2; pu.u[3] = u3;                  \
        PAOUT[c] = pu.v;                                                         \
    }

// PV of one tile: acc += PAOUT . V
#define ATTN_PV(SLOT, PAOUT)                                                     \
    {                                                                            \
        const char* Vb = (const char*)(&Vs[0][0]) + ((SLOT) << 13);              \
        _Pragma("unroll") for (int nb = 0; nb < 2; ++nb) {                       \
            bf16x8 vf[4];                                                        \
            _Pragma("unroll") for (int c = 0; c < 4; ++c)                        \
                vf[c] = *(const bf16x8*)(Vb + loff[nb][c]);                      \
            __builtin_amdgcn_s_setprio(1);                                       \
            _Pragma("unroll") for (int c = 0; c < 4; ++c)                        \
                acc[nb] = __builtin_amdgcn_mfma_f32_32x32x16_bf16(               \
                    PAOUT[c], vf[c], acc[nb], 0, 0, 0);                          \
            __builtin_amdgcn_s_setprio(0);                                       \
        }                                                                        \
    }

#pragma unroll 1
    for (int i = 0; i < 16; ++i) {
        const int t = 2 * i;
        if (i < 15) {
            stageKV((t + 2) & 3, t + 2);
            stageKV((t + 3) & 3, t + 3);
        }
        f32x16 st0[2] = {}, st1[2] = {};
        bf16x8 pa0[4], pa1[4];
        ATTN_QK((t) & 3, st0);          // MFMA
        ATTN_QK((t + 1) & 3, st1);      // MFMA (independent of st0)
        ATTN_SM(st0, pa0);              // VALU/TRANS — overlaps st1's pipe time
        ATTN_PV((t) & 3, pa0);          // MFMA
        ATTN_SM(st1, pa1);              // VALU/TRANS — overlaps PV(t)'s pipe time
        ATTN_PV((t + 1) & 3, pa1);      // MFMA
        __syncthreads();                // drains stage vmcnt + guards ring reuse
    }
#undef ATTN_QK
#undef ATTN_SM
#undef ATTN_PV

    rs += __shfl_xor(rs, 32);
    const int bb = bh >> 4, hd = bh & 15;
#pragma unroll
    for (int r = 0; r < 16; ++r) {
        int ql = (r & 3) + 8 * (r >> 2) + 4 * hh;
        float inv = 1.0f / __shfl(rs, ql);
        int srow = qt * 128 + w * 32 + ql;
#pragma unroll
        for (int nb = 0; nb < 2; ++nb) {
            int col = hd * 64 + nb * 32 + l31;
            ao[((size_t)bb * S_ + srow) * D_ + col] = f2bf(acc[nb][r] * inv);
        }
    }
}

// ---------------------------------------------------------------- launch
extern "C" void kernel_launch(void* const* d_in, const int* in_sizes, int n_in,
                              void* d_out, int out_size, void* d_ws, size_t ws_size,
                              hipStream_t stream) {
    const float* q  = (const float*)d_in[0];
    const float* k  = (const float*)d_in[1];
    const float* v  = (const float*)d_in[2];
    const float* Wq = (const float*)d_in[3];
    const float* bq = (const float*)d_in[4];
    const float* Wk = (const float*)d_in[5];
    const float* bk = (const float*)d_in[6];
    const float* Wv = (const float*)d_in[7];
    const float* bv = (const float*)d_in[8];
    const float* Wo = (const float*)d_in[9];
    const float* bo = (const float*)d_in[10];

    char* ws = (char*)d_ws;
    u16* qb  = (u16*)(ws);                  // 8 MiB
    u16* kb  = (u16*)(ws + (8u  << 20));    // 8 MiB (reused as attn-out)
    u16* vb  = (u16*)(ws + (16u << 20));    // 8 MiB
    u16* Wqb = (u16*)(ws + (24u << 20));    // 2 MiB each
    u16* Wkb = (u16*)(ws + (26u << 20));
    u16* Wvb = (u16*)(ws + (28u << 20));
    u16* Wob = (u16*)(ws + (30u << 20));
    u16* qhb = (u16*)(ws + (32u << 20));    // 8 MiB [B,H,S,DK]
    u16* khb = (u16*)(ws + (40u << 20));    // 8 MiB [B,H,S,DK]
    u16* Vtb = (u16*)(ws + (48u << 20));    // 8 MiB [BH,DK,S]
    u16* aob = kb;                          // alias: kb dead after qkv

    cast_all_kernel<<<8192, 256, 0, stream>>>(q, k, v, Wq, Wk, Wv, Wo,
                                              qb, kb, vb, Wqb, Wkb, Wvb, Wob);

    qkv256_kernel<<<192, 512, 0, stream>>>(
        qb, kb, vb, Wqb, Wkb, Wvb, bq, bk, bv, qhb, khb, Vtb);

    attn_kernel<<<512, 256, 0, stream>>>(qhb, khb, Vtb, aob);

    oproj_kernel<<<512, 256, 0, stream>>>(aob, Wob, bo, (float*)d_out);
}

// Round 18
// 110.604 us; speedup vs baseline: 1.6836x; 1.0239x over previous
//
#include <hip/hip_runtime.h>
#include <stdint.h>

// Problem constants
#define B_  2
#define S_  2048
#define D_  1024
#define H_  16
#define DK_ 64

typedef unsigned short u16;
typedef __attribute__((ext_vector_type(8))) __bf16 bf16x8;
typedef __attribute__((ext_vector_type(4))) float f32x4;
typedef __attribute__((ext_vector_type(16))) float f32x16;
typedef __attribute__((ext_vector_type(4))) short short4v;
typedef __attribute__((ext_vector_type(8))) short short8v;

// f32 -> bf16 round-to-nearest-even (scalar, epilogue use)
static __device__ __forceinline__ u16 f2bf(float f) {
    union { float f; uint32_t u; } v; v.f = f;
    return (u16)((v.u + 0x7fffu + ((v.u >> 16) & 1u)) >> 16);
}
static __device__ __forceinline__ uint32_t pk2bf(float x, float y) {
    return (uint32_t)f2bf(x) | ((uint32_t)f2bf(y) << 16);
}
// HW packed f32x2 -> bf16x2 (RNE) — 1 VALU op (T12 primitive)
static __device__ __forceinline__ uint32_t cvtpk_bf16(float lo, float hi) {
    uint32_t r; asm("v_cvt_pk_bf16_f32 %0, %1, %2" : "=v"(r) : "v"(lo), "v"(hi));
    return r;
}
// raw 2^x
static __device__ __forceinline__ float exp2f_fast(float x) {
    float r; asm("v_exp_f32 %0, %1" : "=v"(r) : "v"(x)); return r;
}

// async global->LDS, 16B per lane. LDS dest = wave-uniform base + lane*16.
#define GLOAD16(gp, lp) \
    __builtin_amdgcn_global_load_lds((const __attribute__((address_space(1))) void*)(gp), \
                                     (__attribute__((address_space(3))) void*)(lp), 16, 0, 0)

// Universal LDS 16B-slot swizzle: phys = lin ^ ((lin>>3)&7). Involution.
static __device__ __forceinline__ int swz(int lin) { return lin ^ ((lin >> 3) & 7); }
// attn swizzle: also fold row bits 3-4 into the bank-group (involution).
static __device__ __forceinline__ int swz2(int lin) {
    return lin ^ ((lin >> 3) & 7) ^ ((lin >> 6) & 3);
}

// XCD-aware bijective block swizzle (nwg % 8 == 0): physical bid -> logical.
static __device__ __forceinline__ int xcd_swz(int bid, int cpx) {
    return (bid & 7) * cpx + (bid >> 3);
}

// ------------------------------------------------------------- fused cast
__global__ __launch_bounds__(256) void cast_all_kernel(
        const float* __restrict__ q, const float* __restrict__ k, const float* __restrict__ v,
        const float* __restrict__ Wq, const float* __restrict__ Wk,
        const float* __restrict__ Wv, const float* __restrict__ Wo,
        u16* __restrict__ qb, u16* __restrict__ kb, u16* __restrict__ vb,
        u16* __restrict__ Wqb, u16* __restrict__ Wkb, u16* __restrict__ Wvb,
        u16* __restrict__ Wob) {
    int blk = blockIdx.x;
    const float* src; u16* dst; int off;
    if (blk < 2048)      { src = q;  dst = qb;  off = blk; }
    else if (blk < 4096) { src = k;  dst = kb;  off = blk - 2048; }
    else if (blk < 6144) { src = v;  dst = vb;  off = blk - 4096; }
    else if (blk < 6656) { src = Wq; dst = Wqb; off = blk - 6144; }
    else if (blk < 7168) { src = Wk; dst = Wkb; off = blk - 6656; }
    else if (blk < 7680) { src = Wv; dst = Wvb; off = blk - 7168; }
    else                 { src = Wo; dst = Wob; off = blk - 7680; }
    int i = (off * 256 + threadIdx.x) * 8;
    float4 a = *(const float4*)(src + i);
    float4 b = *(const float4*)(src + i + 4);
    uint4 r;
    r.x = pk2bf(a.x, a.y); r.y = pk2bf(a.z, a.w);
    r.z = pk2bf(b.x, b.y); r.w = pk2bf(b.z, b.w);
    *(uint4*)(void*)(dst + i) = r;
}

// ---------------------------------------------------------------------------
// QKV projection: 256x256 tile, BK=64, 8 waves (2Mx4N), 8-phase schedule.
// ---------------------------------------------------------------------------
__device__ __forceinline__ void stage_half(const u16* __restrict__ src,
        int R0, int kt, u16* dst, int tid) {
#pragma unroll
    for (int r = 0; r < 2; ++r) {
        int s = tid + (r << 9);                 // 512 threads, 1024 slots
        int lin = s ^ ((s >> 3) & 7);           // inverse swizzle (involution)
        int row = lin >> 3, ch = lin & 7;       // 128B rows: 8 chunks of 16B
        GLOAD16(src + (size_t)(R0 + row) * 1024 + (kt << 6) + (ch << 3),
                (char*)dst + ((r << 9) + ((tid >> 6) << 6)) * 16);
    }
}

#define VM4  asm volatile("s_waitcnt vmcnt(4)" ::: "memory")
#define VM0  asm volatile("s_waitcnt vmcnt(0)" ::: "memory")

#define PHASE(QQ, MP, LOADB, STAGE_STMT, VM_STMT)                                \
    {                                                                            \
        bf16x8 afr[2][2];                                                        \
        if (LOADB) {                                                             \
            _Pragma("unroll") for (int fn = 0; fn < 4; ++fn)                     \
            _Pragma("unroll") for (int ks = 0; ks < 2; ++ks) {                   \
                int lin = (brow0 + fn * 16 + (lane & 15)) * 8 + ks * 4 + (lane >> 4); \
                bfr[fn][ks] = *(const bf16x8*)(Bhb[QQ] + swz(lin) * 16);         \
            }                                                                    \
        }                                                                        \
        _Pragma("unroll") for (int fo = 0; fo < 2; ++fo)                         \
        _Pragma("unroll") for (int ks = 0; ks < 2; ++ks) {                       \
            int lin = ((MP) * 32 + fo * 16 + (lane & 15)) * 8 + ks * 4 + (lane >> 4); \
            afr[fo][ks] = *(const bf16x8*)(Ahb[QQ] + swz(lin) * 16);             \
        }                                                                        \
        STAGE_STMT;                                                              \
        VM_STMT;                                                                 \
        __builtin_amdgcn_s_barrier();                                            \
        __builtin_amdgcn_sched_barrier(0);                                       \
        __builtin_amdgcn_s_setprio(1);                                           \
        _Pragma("unroll") for (int fo = 0; fo < 2; ++fo)                         \
        _Pragma("unroll") for (int ks = 0; ks < 2; ++ks)                         \
        _Pragma("unroll") for (int fn = 0; fn < 4; ++fn)                         \
            acc[(MP) * 2 + fo][fn] = __builtin_amdgcn_mfma_f32_16x16x32_bf16(    \
                afr[fo][ks], bfr[fn][ks], acc[(MP) * 2 + fo][fn], 0, 0, 0);      \
        __builtin_amdgcn_s_setprio(0);                                           \
        __builtin_amdgcn_s_barrier();                                            \
        __builtin_amdgcn_sched_barrier(0);                                       \
    }

__global__ __launch_bounds__(512, 2) void qkv256_kernel(
        const u16* __restrict__ qX, const u16* __restrict__ kX, const u16* __restrict__ vX,
        const u16* __restrict__ Wq, const u16* __restrict__ Wk, const u16* __restrict__ Wv,
        const float* __restrict__ bq, const float* __restrict__ bk, const float* __restrict__ bv,
        u16* __restrict__ qo, u16* __restrict__ ko, u16* __restrict__ vt) {
    __shared__ __align__(16) u16 lds[65536];    // 128 KB
    const int tid = threadIdx.x, lane = tid & 63, w = tid >> 6;
    const int wm = w >> 2, wn = w & 3;          // 2 x 4 waves
    const int lg = xcd_swz(blockIdx.x, 24);     // 192 = 8 * 24
    const int which = lg >> 6;                  // 0=Q 1=K 2=V
    const int rem = lg & 63;
    const int n0 = (rem >> 4) << 8;             // 4 n-tiles
    const int m0 = (rem & 15) << 8;             // 16 m-tiles (m-minor: share W panel)
    const u16* X = which == 0 ? qX : (which == 1 ? kX : vX);
    const u16* W = which == 0 ? Wq : (which == 1 ? Wk : Wv);
    const float* bias = which == 0 ? bq : (which == 1 ? bk : bv);

    u16* Abase = lds;              // [dbuf][half][1024 slots]
    u16* Bbase = lds + 32768;

    // prologue: tile0 {A0,A1,B0,B1}; tile1 {B0,B1}
    stage_half(X, m0,        0, Abase + 0,             tid);
    stage_half(X, m0 + 128,  0, Abase + 8192,          tid);
    stage_half(W, n0,        0, Bbase + 0,             tid);
    stage_half(W, n0 + 128,  0, Bbase + 8192,          tid);
    stage_half(W, n0,        1, Bbase + 16384,         tid);
    stage_half(W, n0 + 128,  1, Bbase + 16384 + 8192,  tid);
    VM4;                                         // tile0's 4 halves landed
    __builtin_amdgcn_s_barrier();
    __builtin_amdgcn_sched_barrier(0);

    f32x4 acc[8][4] = {};
    bf16x8 bfr[4][2];
    const char* Ahb[2] = { (const char*)(Abase + wm * 8192),
                           (const char*)(Abase + 16384 + wm * 8192) };
    const char* Bhb[2] = { (const char*)(Bbase + (wn >> 1) * 8192),
                           (const char*)(Bbase + 16384 + (wn >> 1) * 8192) };
    const int brow0 = (wn & 1) * 64;

#pragma unroll 1
    for (int i = 0; i < 8; ++i) {
        const int t0 = 2 * i, t1 = 2 * i + 1;
        const bool nl = (i < 7);                 // not-last
        // p1..p4: compute t0 (buf 0)
        PHASE(0, 0, true,  stage_half(X, m0,       t1,     Abase + 16384,        tid), (void)0);
        PHASE(0, 1, false, stage_half(X, m0 + 128, t1,     Abase + 16384 + 8192, tid), (void)0);
        PHASE(0, 2, false, if (nl) stage_half(W, n0,       t0 + 2, Bbase + 0,    tid), (void)0);
        PHASE(0, 3, false, if (nl) stage_half(W, n0 + 128, t0 + 2, Bbase + 8192, tid),
              if (nl) { VM4; } else { VM0; });
        // p5..p8: compute t1 (buf 1)
        PHASE(1, 0, true,  if (nl) stage_half(X, m0,       t0 + 2, Abase + 0,    tid), (void)0);
        PHASE(1, 1, false, if (nl) stage_half(X, m0 + 128, t0 + 2, Abase + 8192, tid), (void)0);
        PHASE(1, 2, false, if (nl) stage_half(W, n0,       t1 + 2, Bbase + 16384, tid), (void)0);
        PHASE(1, 3, false, if (nl) stage_half(W, n0 + 128, t1 + 2, Bbase + 16384 + 8192, tid),
              if (nl) { VM4; });
    }

    // ---------------- epilogues
    if (which < 2) {
        u16* out = which == 0 ? qo : ko;
        const float scale = which == 0 ? 0.1803368801111883f : 1.0f; // (1/8)*log2(e)
#pragma unroll
        for (int fn = 0; fn < 4; ++fn) {
            int n = n0 + wn * 64 + fn * 16 + (lane & 15);
            float bb = bias[n];
            int h = n >> 6, dk = n & 63;
#pragma unroll
            for (int fm = 0; fm < 8; ++fm)
#pragma unroll
                for (int j = 0; j < 4; ++j) {
                    int m = m0 + wm * 128 + fm * 16 + (lane >> 4) * 4 + j;
                    int b = m >> 11, s = m & 2047;
                    out[((size_t)(b * H_ + h) * S_ + s) * DK_ + dk] =
                        f2bf((acc[fm][fn][j] + bb) * scale);
                }
        }
    } else {
        // V: per-wave private 16KB LDS transpose [128 s][64 dk] -> [64 dk][128 s]
        __syncthreads();                         // all compute LDS reads done
        u16* wl = lds + w * 8192;
#pragma unroll
        for (int fn = 0; fn < 4; ++fn) {
            int dk = fn * 16 + (lane & 15);
            float bb = bias[n0 + wn * 64 + dk];
            int xr = (dk & 7) << 3;
#pragma unroll
            for (int fm = 0; fm < 8; ++fm) {
                int sl = fm * 16 + (lane >> 4) * 4;
                short4v p;
#pragma unroll
                for (int j = 0; j < 4; ++j) p[j] = (short)f2bf(acc[fm][fn][j] + bb);
                *(short4v*)(void*)&wl[dk * 128 + (sl ^ xr)] = p;
            }
        }
        int mrow = m0 + wm * 128;
        int b = mrow >> 11, sbase = mrow & 2047;
        int h = (n0 >> 6) + wn;
        u16* dst = vt + ((size_t)(b * H_ + h) * DK_) * S_ + sbase;
#pragma unroll
        for (int oc = 0; oc < 8; ++oc)
#pragma unroll
            for (int ic = 0; ic < 2; ++ic) {
                int dk = oc * 8 + (lane >> 3);
                int sc = ic * 8 + (lane & 7);
                short8v vv = *(const short8v*)(const void*)
                    &wl[dk * 128 + ((sc * 8) ^ ((dk & 7) << 3))];
                *(short8v*)(void*)(dst + (size_t)dk * S_ + sc * 8) = vv;
            }
    }
}

// ---------------------- Output projection: 64x128 tile, 2-phase dbuf.
// Grid 512 = 64 m-tiles x 8 n-tiles -> 2 blocks/CU, 2 waves/SIMD.
__global__ __launch_bounds__(256) void oproj_kernel(
        const u16* __restrict__ X, const u16* __restrict__ W,
        const float* __restrict__ bias, float* __restrict__ out) {
    __shared__ __align__(16) u16 lds[12288];
    const int tid = threadIdx.x, lane = tid & 63, w = tid >> 6;
    const int wm = w >> 1, wn = w & 1;
    const int bid = xcd_swz(blockIdx.x, 64);    // 512 = 8 * 64
    const int m0 = (bid >> 3) << 6;             // 64 m-tiles of 64 rows
    const int n0 = (bid & 7) << 7;              // 8 n-tiles of 128 cols
    u16* As = lds;          // [2][2048]
    u16* Bs = lds + 4096;   // [2][4096]

    auto stage = [&](int bi, int kt) {
        {   // A: 64x32 = 256 slots, 1 load/thread
            int lin = tid ^ ((tid >> 3) & 7);
            int row = lin >> 2, ch = lin & 3;
            GLOAD16(X + (size_t)(m0 + row) * 1024 + (kt << 5) + (ch << 3),
                    (char*)(As + bi * 2048) + (w << 6) * 16);
        }
#pragma unroll
        for (int r = 0; r < 2; ++r) {   // B: 128x32 = 512 slots, 2 loads/thread
            int s = tid + (r << 8);
            int lin = s ^ ((s >> 3) & 7);
            int row = lin >> 2, ch = lin & 3;
            GLOAD16(W + (size_t)(n0 + row) * 1024 + (kt << 5) + (ch << 3),
                    (char*)(Bs + bi * 4096) + ((r << 8) + (w << 6)) * 16);
        }
    };

    f32x4 acc[2][4] = {};
    stage(0, 0);
    asm volatile("s_waitcnt vmcnt(0)" ::: "memory");
    __syncthreads();
#pragma unroll 1
    for (int kt = 0; kt < 32; ++kt) {
        const int cur = kt & 1;
        if (kt < 31) stage(cur ^ 1, kt + 1);    // prefetch next tile (in flight)
        const char* Ab = (const char*)(As + cur * 2048);
        const char* Bb = (const char*)(Bs + cur * 4096);
        bf16x8 a[2], b[4];
#pragma unroll
        for (int f = 0; f < 2; ++f) {
            int rowa = wm * 32 + f * 16 + (lane & 15);
            a[f] = *(const bf16x8*)(Ab + swz(rowa * 4 + (lane >> 4)) * 16);
        }
#pragma unroll
        for (int f = 0; f < 4; ++f) {
            int rowb = wn * 64 + f * 16 + (lane & 15);
            b[f] = *(const bf16x8*)(Bb + swz(rowb * 4 + (lane >> 4)) * 16);
        }
#pragma unroll
        for (int fm = 0; fm < 2; ++fm)
#pragma unroll
            for (int fn = 0; fn < 4; ++fn)
                acc[fm][fn] = __builtin_amdgcn_mfma_f32_16x16x32_bf16(
                    a[fm], b[fn], acc[fm][fn], 0, 0, 0);
        __syncthreads();   // drains vmcnt (prefetch landed) + lgkm, guards buf reuse
    }

    // epilogue: + bias, fp32 store
#pragma unroll
    for (int fn = 0; fn < 4; ++fn) {
        int n = n0 + wn * 64 + fn * 16 + (lane & 15);
        float bb = bias[n];
#pragma unroll
        for (int fm = 0; fm < 2; ++fm)
#pragma unroll
            for (int j = 0; j < 4; ++j) {
                int m = m0 + wm * 32 + fm * 16 + (lane >> 4) * 4 + j;
                out[(size_t)m * 1024 + n] = acc[fm][fn][j] + bb;
            }
    }
}

// ------------------------------------------------------------ flash attention
// R12 math/template with 512-thread blocks: 8 waves x 32 q-rows = 256 rows
// per block, K/V staged ONCE per block (each thread: 1 K + 1 V GLOAD16 per
// tile — staging per output halves), 2 blocks/CU -> 4 waves/SIMD (2x R12's
// occupancy). 4-slot KV ring, 2-tile iterations, one barrier per 128 keys.
__global__ __launch_bounds__(512, 2) void attn_kernel(
        const u16* __restrict__ qh, const u16* __restrict__ kh,
        const u16* __restrict__ Vt, u16* __restrict__ ao) {
    __shared__ __align__(16) u16 Ks[4][4096];    // 32KB ring [64 key][64 dk]
    __shared__ __align__(16) u16 Vs[4][4096];    // 32KB ring [64 dk][64 key]

    const int tid = threadIdx.x, lane = tid & 63, w = tid >> 6;   // w in 0..7
    const int l31 = lane & 31, hh = lane >> 5;
    const int lg = xcd_swz(blockIdx.x, 32);      // 256 = 8 * 32
    const int bh = lg >> 3, qt = lg & 7;         // 8 q-tiles of 256 rows
    const u16* qg = qh + ((size_t)bh * S_ + qt * 256) * DK_;
    const u16* kg = kh + (size_t)bh * S_ * DK_;
    const u16* vg = Vt + (size_t)bh * DK_ * S_;

    // ---- hoisted stage addressing: 512 threads cover 512 16B-slots each of
    // K and V per tile (1 GLOAD16 each).
    const int lin0 = swz2(tid);
    const u16* ksrc0 = kg + (lin0 >> 3) * 64 + ((lin0 & 7) << 3);
    const u16* vsrc0 = vg + (size_t)(lin0 >> 3) * S_ + ((lin0 & 7) << 3);
    char* kdst0 = (char*)(&Ks[0][0]) + (w << 6) * 16;
    char* vdst0 = (char*)(&Vs[0][0]) + (w << 6) * 16;

    auto stageKV = [&](int slot, int kt) {
        const int sb = slot << 13;               // slot * 8192 bytes
        GLOAD16(ksrc0 + (kt << 12), kdst0 + sb);
        GLOAD16(vsrc0 + (kt << 6),  vdst0 + sb);
    };

    // ---- hoisted LDS read byte-offsets (same table for K and V fragments)
    int loff[2][4];
#pragma unroll
    for (int b = 0; b < 2; ++b)
#pragma unroll
        for (int c = 0; c < 4; ++c)
            loff[b][c] = swz2((b * 32 + l31) * 8 + c * 2 + hh) * 16;

    // prologue: KV tiles 0,1 + Q fragments direct from global
    stageKV(0, 0);
    stageKV(1, 1);
    bf16x8 qf[4];
#pragma unroll
    for (int c = 0; c < 4; ++c)
        qf[c] = *(const bf16x8*)(qg + (size_t)(w * 32 + l31) * 64 + c * 16 + hh * 8);
    asm volatile("s_waitcnt vmcnt(0)" ::: "memory");
    __syncthreads();

    f32x16 acc[2] = {};
    float rs = 0.f;

// QK^T of one tile into ST (2x f32x16)
#define ATTN_QK(SLOT, ST)                                                        \
    {                                                                            \
        const char* Kb = (const char*)(&Ks[0][0]) + ((SLOT) << 13);              \
        _Pragma("unroll") for (int kb = 0; kb < 2; ++kb) {                       \
            bf16x8 kf[4];                                                        \
            _Pragma("unroll") for (int c = 0; c < 4; ++c)                        \
                kf[c] = *(const bf16x8*)(Kb + loff[kb][c]);                      \
            __builtin_amdgcn_s_setprio(1);                                       \
            _Pragma("unroll") for (int c = 0; c < 4; ++c)                        \
                ST[kb] = __builtin_amdgcn_mfma_f32_32x32x16_bf16(                \
                    kf[c], qf[c], ST[kb], 0, 0, 0);                              \
            __builtin_amdgcn_s_setprio(0);                                       \
        }                                                                        \
    }

// softmax numerator + in-register repack of ST into PAOUT; rs accumulate
#define ATTN_SM(ST, PAOUT)                                                       \
    _Pragma("unroll") for (int c = 0; c < 4; ++c) {                              \
        const int kb = c >> 1, o = (c & 1) * 8;                                  \
        float e0 = exp2f_fast(ST[kb][o + 0]);                                    \
        float e1 = exp2f_fast(ST[kb][o + 1]);                                    \
        float e2 = exp2f_fast(ST[kb][o + 2]);                                    \
        float e3 = exp2f_fast(ST[kb][o + 3]);                                    \
        float e4 = exp2f_fast(ST[kb][o + 4]);                                    \
        float e5 = exp2f_fast(ST[kb][o + 5]);                                    \
        float e6 = exp2f_fast(ST[kb][o + 6]);                                    \
        float e7 = exp2f_fast(ST[kb][o + 7]);                                    \
        rs += ((e0 + e1) + (e2 + e3)) + ((e4 + e5) + (e6 + e7));                 \
        uint32_t u0 = cvtpk_bf16(e0, e1);                                        \
        uint32_t u1 = cvtpk_bf16(e2, e3);                                        \
        uint32_t u2 = cvtpk_bf16(e4, e5);                                        \
        uint32_t u3 = cvtpk_bf16(e6, e7);                                        \
        asm volatile("v_permlane32_swap_b32 %0, %1" : "+v"(u0), "+v"(u2));       \
        asm volatile("v_permlane32_swap_b32 %0, %1" : "+v"(u1), "+v"(u3));       \
        union { uint32_t u[4]; bf16x8 v; } pu;                                   \
        pu.u[0] = u0; pu.u[1] = u1; pu.u[2] = u2; pu.u[3] = u3;                  \
        PAOUT[c] = pu.v;                                                         \
    }

// PV of one tile: acc += PAOUT . V
#define ATTN_PV(SLOT, PAOUT)                                                     \
    {                                                                            \
        const char* Vb = (const char*)(&Vs[0][0]) + ((SLOT) << 13);              \
        _Pragma("unroll") for (int nb = 0; nb < 2; ++nb) {                       \
            bf16x8 vf[4];                                                        \
            _Pragma("unroll") for (int c = 0; c < 4; ++c)                        \
                vf[c] = *(const bf16x8*)(Vb + loff[nb][c]);                      \
            __builtin_amdgcn_s_setprio(1);                                       \
            _Pragma("unroll") for (int c = 0; c < 4; ++c)                        \
                acc[nb] = __builtin_amdgcn_mfma_f32_32x32x16_bf16(               \
                    PAOUT[c], vf[c], acc[nb], 0, 0, 0);                          \
            __builtin_amdgcn_s_setprio(0);                                       \
        }                                                                        \
    }

#pragma unroll 1
    for (int i = 0; i < 16; ++i) {
        const int t = 2 * i;
        if (i < 15) {
            stageKV((t + 2) & 3, t + 2);
            stageKV((t + 3) & 3, t + 3);
        }
        f32x16 st0[2] = {}, st1[2] = {};
        bf16x8 pa0[4], pa1[4];
        ATTN_QK((t) & 3, st0);          // MFMA
        ATTN_QK((t + 1) & 3, st1);      // MFMA (independent of st0)
        ATTN_SM(st0, pa0);              // VALU/TRANS — overlaps st1's pipe time
        ATTN_PV((t) & 3, pa0);          // MFMA
        ATTN_SM(st1, pa1);              // VALU/TRANS — overlaps PV(t)'s pipe time
        ATTN_PV((t + 1) & 3, pa1);      // MFMA
        __syncthreads();                // drains stage vmcnt + guards ring reuse
    }
#undef ATTN_QK
#undef ATTN_SM
#undef ATTN_PV

    rs += __shfl_xor(rs, 32);
    const int bb = bh >> 4, hd = bh & 15;
#pragma unroll
    for (int r = 0; r < 16; ++r) {
        int ql = (r & 3) + 8 * (r >> 2) + 4 * hh;
        float inv = 1.0f / __shfl(rs, ql);
        int srow = qt * 256 + w * 32 + ql;
#pragma unroll
        for (int nb = 0; nb < 2; ++nb) {
            int col = hd * 64 + nb * 32 + l31;
            ao[((size_t)bb * S_ + srow) * D_ + col] = f2bf(acc[nb][r] * inv);
        }
    }
}

// ---------------------------------------------------------------- launch
extern "C" void kernel_launch(void* const* d_in, const int* in_sizes, int n_in,
                              void* d_out, int out_size, void* d_ws, size_t ws_size,
                              hipStream_t stream) {
    const float* q  = (const float*)d_in[0];
    const float* k  = (const float*)d_in[1];
    const float* v  = (const float*)d_in[2];
    const float* Wq = (const float*)d_in[3];
    const float* bq = (const float*)d_in[4];
    const float* Wk = (const float*)d_in[5];
    const float* bk = (const float*)d_in[6];
    const float* Wv = (const float*)d_in[7];
    const float* bv = (const float*)d_in[8];
    const float* Wo = (const float*)d_in[9];
    const float* bo = (const float*)d_in[10];

    char* ws = (char*)d_ws;
    u16* qb  = (u16*)(ws);                  // 8 MiB
    u16* kb  = (u16*)(ws + (8u  << 20));    // 8 MiB (reused as attn-out)
    u16* vb  = (u16*)(ws + (16u << 20));    // 8 MiB
    u16* Wqb = (u16*)(ws + (24u << 20));    // 2 MiB each
    u16* Wkb = (u16*)(ws + (26u << 20));
    u16* Wvb = (u16*)(ws + (28u << 20));
    u16* Wob = (u16*)(ws + (30u << 20));
    u16* qhb = (u16*)(ws + (32u << 20));    // 8 MiB [B,H,S,DK]
    u16* khb = (u16*)(ws + (40u << 20));    // 8 MiB [B,H,S,DK]
    u16* Vtb = (u16*)(ws + (48u << 20));    // 8 MiB [BH,DK,S]
    u16* aob = kb;                          // alias: kb dead after qkv

    cast_all_kernel<<<8192, 256, 0, stream>>>(q, k, v, Wq, Wk, Wv, Wo,
                                              qb, kb, vb, Wqb, Wkb, Wvb, Wob);

    qkv256_kernel<<<192, 512, 0, stream>>>(
        qb, kb, vb, Wqb, Wkb, Wvb, bq, bk, bv, qhb, khb, Vtb);

    attn_kernel<<<256, 512, 0, stream>>>(qhb, khb, Vtb, aob);

    oproj_kernel<<<512, 256, 0, stream>>>(aob, Wob, bo, (float*)d_out);
}